// Round 7
// baseline (308.339 us; speedup 1.0000x reference)
//
#include <hip/hip_runtime.h>

#define L    2048
#define D    128
#define NH   16
#define TILE 128

typedef float  floatx4 __attribute__((ext_vector_type(4)));
typedef float  floatx2 __attribute__((ext_vector_type(2)));
typedef short  shortx8 __attribute__((ext_vector_type(8)));

// quantize-dequantize a pair via HW OCP e4m3 conversion (gfx950: RNE, saturate
// +-448, subnormal grid down to 2^-9) — semantically identical to the ref's
// exponent-clamped round-to-nearest quantizer.
__device__ __forceinline__ floatx2 quant2(float a, float b) {
    int p = __builtin_amdgcn_cvt_pk_fp8_f32(a, b, 0, false);
    return __builtin_amdgcn_cvt_pk_f32_fp8(p, false);
}

// fp32 -> quantize -> exact bf16 bits (quantized values have <=4-bit
// significands, so truncation to bf16 is exact). blockIdx.y: 0 = q, 1 = k.
__global__ __launch_bounds__(256) void quant_qk_bf16(const float* __restrict__ q,
                                                     const float* __restrict__ k,
                                                     unsigned short* __restrict__ qb,
                                                     unsigned short* __restrict__ kb) {
    const float* __restrict__ src = blockIdx.y ? k : q;
    unsigned short* __restrict__ dst = blockIdx.y ? kb : qb;
    int i = blockIdx.x * 256 + threadIdx.x;
    float4 v = reinterpret_cast<const float4*>(src)[i];
    floatx2 q0 = quant2(v.x, v.y);
    floatx2 q1 = quant2(v.z, v.w);
    ushort4 o;
    o.x = (unsigned short)(__float_as_uint(q0.x) >> 16);
    o.y = (unsigned short)(__float_as_uint(q0.y) >> 16);
    o.z = (unsigned short)(__float_as_uint(q1.x) >> 16);
    o.w = (unsigned short)(__float_as_uint(q1.y) >> 16);
    reinterpret_cast<ushort4*>(dst)[i] = o;
}

// HEAD-LOOP + DOUBLE-BUFFER + T14 split-staging version.
// Grid (16 j, 16 i, 2 head-groups) = 512 blocks; 128 KB LDS -> 1 block/CU.
// Two 64 KB tile buffers alternate per head:
//   iter h: cur holds tiles(h); other buffer (oth) is free (its Os was read
//   back last iter). Schedule: [A] barrier -> issue global loads(h+1)->regs
//   (latency hides under MFMA+epilogue) -> frag-read cur + MFMA + epilogue
//   -> ds_write regs -> oth -> [B] barrier (frag reads done) -> Os(h)
//   overlays cur -> [C] barrier -> coalesced readback+store. 3 barriers/iter,
//   staging entirely off the serial tail (round-6 had 4 barriers with cold
//   staging loads in the post-readback slot).
__global__ __launch_bounds__(512, 2) void score_kernel(
    const unsigned short* __restrict__ qb, const unsigned short* __restrict__ kb,
    const float* __restrict__ am, const int* __restrict__ kp,
    float* __restrict__ out)
{
    __shared__ __align__(16) unsigned char smem[128 * 1024];

    const int hg = blockIdx.z;          // head group (0/1): heads hg*8 .. hg*8+7
    const int i0 = blockIdx.y * TILE;
    const int j0 = blockIdx.x * TILE;
    const int t  = threadIdx.x;

    const int wave = t >> 6;
    const int lane = t & 63;
    const int wr = (wave >> 2) * 64;   // q-row offset of this wave   (0/64)
    const int wc = (wave & 3) * 32;    // k-col offset of this wave   (0/32/64/96)
    const int lr = lane & 15;
    const int kq = lane >> 4;

    // ---- per-block invariants: kp flags + quantized mask fragment (regs) ----
    int4 pv[2];
    #pragma unroll
    for (int n = 0; n < 2; ++n)
        pv[n] = *reinterpret_cast<const int4*>(&kp[j0 + wc + n * 16 + kq * 4]);

    ushort4 mld[4][2];                 // quantized mask as bf16 bits (exact)
    #pragma unroll
    for (int m = 0; m < 4; ++m) {
        const size_t gi = (size_t)(i0 + wr + m * 16 + lr);
        #pragma unroll
        for (int n = 0; n < 2; ++n) {
            float4 mv = *reinterpret_cast<const float4*>(
                am + gi * L + (j0 + wc + n * 16 + kq * 4));
            floatx2 m01 = quant2(mv.x, mv.y);
            floatx2 m23 = quant2(mv.z, mv.w);
            mld[m][n].x = (unsigned short)(__float_as_uint(m01.x) >> 16);
            mld[m][n].y = (unsigned short)(__float_as_uint(m01.y) >> 16);
            mld[m][n].z = (unsigned short)(__float_as_uint(m23.x) >> 16);
            mld[m][n].w = (unsigned short)(__float_as_uint(m23.y) >> 16);
        }
    }

    const float QSCALE = 0.0859375f;   // quant_fp8_e4m3(128^-0.5), exact
    // Masked value must stay FINITE after a bf16 RNE cast (harness compares
    // through bf16; -FLT_MAX would round to bf16 -inf -> inf-inf -> NaN).
    const float NEG_BIG = -1.0e38f;

    uint4 sq[4], sk[4];                // in-flight staging regs (T14)

    // ---- prologue: stage head hg*8 into buffer 0 ----
    {
        const int h0 = hg * 8;
        const uint4* qg = reinterpret_cast<const uint4*>(qb + ((size_t)h0 * L + i0) * D);
        const uint4* kg = reinterpret_cast<const uint4*>(kb + ((size_t)h0 * L + j0) * D);
        #pragma unroll
        for (int r = 0; r < 4; ++r) { sq[r] = qg[t + r * 512]; sk[r] = kg[t + r * 512]; }
        uint4* Q0 = reinterpret_cast<uint4*>(smem);
        uint4* K0 = reinterpret_cast<uint4*>(smem + 32768);
        #pragma unroll
        for (int r = 0; r < 4; ++r) {
            const int idx = t + r * 512;
            const int row = idx >> 4;
            const int ss  = (idx & 15) ^ (row & 7);
            Q0[row * 16 + ss] = sq[r];
            K0[row * 16 + ss] = sk[r];
        }
    }

    for (int hh = 0; hh < 8; ++hh) {
        const int h = hg * 8 + hh;
        unsigned char* curb = smem + (size_t)(hh & 1) * 65536;
        unsigned char* othb = smem + (size_t)((hh & 1) ^ 1) * 65536;
        unsigned short* Qs = reinterpret_cast<unsigned short*>(curb);
        unsigned short* Ks = reinterpret_cast<unsigned short*>(curb + 32768);
        floatx4* Os4 = reinterpret_cast<floatx4*>(curb);

        __syncthreads();               // [A] stage(h)->cur visible; oth free

        // ---- prefetch next head's tiles into registers (overlaps MFMA) ----
        if (hh < 7) {
            const uint4* qg = reinterpret_cast<const uint4*>(qb + ((size_t)(h + 1) * L + i0) * D);
            const uint4* kg = reinterpret_cast<const uint4*>(kb + ((size_t)(h + 1) * L + j0) * D);
            #pragma unroll
            for (int r = 0; r < 4; ++r) { sq[r] = qg[t + r * 512]; sk[r] = kg[t + r * 512]; }
        }

        // ---- MFMA phase ----
        floatx4 acc[4][2];
        #pragma unroll
        for (int m = 0; m < 4; ++m)
            #pragma unroll
            for (int n = 0; n < 2; ++n)
                acc[m][n] = (floatx4){0.f, 0.f, 0.f, 0.f};

        #pragma unroll
        for (int ks = 0; ks < 4; ++ks) {
            shortx8 af[4], bfr[2];
            #pragma unroll
            for (int m = 0; m < 4; ++m) {
                const int row = wr + m * 16 + lr;
                const int ss  = (ks * 4 + kq) ^ (row & 7);
                af[m] = *reinterpret_cast<const shortx8*>(&Qs[row * 128 + ss * 8]);
            }
            #pragma unroll
            for (int n = 0; n < 2; ++n) {
                const int row = wc + n * 16 + lr;
                const int ss  = (ks * 4 + kq) ^ (row & 7);
                bfr[n] = *reinterpret_cast<const shortx8*>(&Ks[row * 128 + ss * 8]);
            }
            // SWAPPED: K fragment as A-operand, Q fragment as B-operand.
            #pragma unroll
            for (int m = 0; m < 4; ++m)
                #pragma unroll
                for (int n = 0; n < 2; ++n)
                    acc[m][n] = __builtin_amdgcn_mfma_f32_16x16x32_bf16(bfr[n], af[m], acc[m][n], 0, 0, 0);
        }

        // ---- finish values in registers ----
        #pragma unroll
        for (int m = 0; m < 4; ++m) {
            #pragma unroll
            for (int n = 0; n < 2; ++n) {
                const float m0 = __uint_as_float((unsigned)mld[m][n].x << 16);
                const float m1 = __uint_as_float((unsigned)mld[m][n].y << 16);
                const float m2 = __uint_as_float((unsigned)mld[m][n].z << 16);
                const float m3 = __uint_as_float((unsigned)mld[m][n].w << 16);

                floatx4 a = acc[m][n];
                floatx2 a01 = quant2(a[0], a[1]);
                floatx2 a23 = quant2(a[2], a[3]);
                floatx2 b01 = quant2(a01.x * QSCALE, a01.y * QSCALE);
                floatx2 b23 = quant2(a23.x * QSCALE, a23.y * QSCALE);

                floatx4 o;
                o[0] = pv[n].x ? NEG_BIG : (b01.x + m0);
                o[1] = pv[n].y ? NEG_BIG : (b01.y + m1);
                o[2] = pv[n].z ? NEG_BIG : (b23.x + m2);
                o[3] = pv[n].w ? NEG_BIG : (b23.y + m3);
                acc[m][n] = o;
            }
        }

        // ---- write prefetched tiles into the free buffer (off critical path) ----
        if (hh < 7) {
            uint4* Qo = reinterpret_cast<uint4*>(othb);
            uint4* Ko = reinterpret_cast<uint4*>(othb + 32768);
            #pragma unroll
            for (int r = 0; r < 4; ++r) {
                const int idx = t + r * 512;
                const int row = idx >> 4;
                const int ss  = (idx & 15) ^ (row & 7);
                Qo[row * 16 + ss] = sq[r];
                Ko[row * 16 + ss] = sk[r];
            }
        }

        __syncthreads();               // [B] all frag reads of cur done
        // ---- stage out-tile over cur's Qs/Ks ----
        #pragma unroll
        for (int m = 0; m < 4; ++m) {
            const int row = wr + m * 16 + lr;
            #pragma unroll
            for (int n = 0; n < 2; ++n) {
                const int s = (wc >> 2) + n * 4 + kq;        // 16B slot (0..31)
                Os4[row * 32 + (s ^ (row & 7))] = acc[m][n];
            }
        }
        __syncthreads();               // [C] Os complete

        // ---- coalesced writeback: each wave 2 rows x 512B per instr ----
        #pragma unroll
        for (int i = 0; i < 4; ++i) {
            const int idx = i * 512 + t;        // linear float4 within tile
            const int row = idx >> 5;           // 32 float4 slots per row
            const int s   = idx & 31;
            floatx4 v = Os4[row * 32 + (s ^ (row & 7))];
            reinterpret_cast<floatx4*>(out + ((size_t)h * L + i0 + row) * L + j0)[s] = v;
        }
        // loop-top [A] of next iter guarantees this readback is done before
        // anyone stages h+2 into curb.
    }
}

extern "C" void kernel_launch(void* const* d_in, const int* in_sizes, int n_in,
                              void* d_out, int out_size, void* d_ws, size_t ws_size,
                              hipStream_t stream) {
    const float* q  = (const float*)d_in[0];
    const float* k  = (const float*)d_in[1];
    const float* am = (const float*)d_in[2];
    const int*   kp = (const int*)d_in[3];
    float* out = (float*)d_out;

    char* ws = (char*)d_ws;
    unsigned short* qb = (unsigned short*)ws;                 // 8 MB quantized q (bf16)
    unsigned short* kb = (unsigned short*)(ws + (8u << 20));  // 8 MB quantized k (bf16)

    const int nqk4 = NH * L * D / 4;   // 1,048,576 float4 groups
    dim3 qgrid(nqk4 / 256, 2);
    quant_qk_bf16<<<qgrid, 256, 0, stream>>>(q, k, qb, kb);

    dim3 grid(L / TILE, L / TILE, 2);  // (j, i, head-group), 512 blocks = 1/CU x2
    score_kernel<<<grid, 512, 0, stream>>>(qb, kb, am, kp, out);
}